// Round 1
// baseline (1816.800 us; speedup 1.0000x reference)
//
#include <hip/hip_runtime.h>
#include <hip/hip_bf16.h>
#include <stdint.h>

#define T_TOK 8192
#define DIM   2048
#define NEXP  8
#define HDIM  1408
#define SHDIM 2816

typedef __attribute__((ext_vector_type(8))) short bfrag;   // 8 x bf16 (4 VGPR)
typedef __attribute__((ext_vector_type(4))) float f32x4;

__device__ __forceinline__ short f2bf(float f) {
    union { float f; uint32_t u; } v; v.f = f;
    return (short)((v.u + 0x8000u) >> 16);   // round-half-up bf16
}

__device__ __forceinline__ bfrag cvt8(float4 a, float4 b) {
    bfrag r;
    r[0] = f2bf(a.x); r[1] = f2bf(a.y); r[2] = f2bf(a.z); r[3] = f2bf(a.w);
    r[4] = f2bf(b.x); r[5] = f2bf(b.y); r[6] = f2bf(b.z); r[7] = f2bf(b.w);
    return r;
}

// meta layout (ints): [0..7] counts, [8..15] cursor, [16..24] offsets, floats at +32: s_e[8]

__global__ __launch_bounds__(256) void gate_kernel(
    const float* __restrict__ x, const float* __restrict__ gw,
    int* __restrict__ sel, int* __restrict__ meta, float* __restrict__ s_e)
{
    __shared__ float g[NEXP * DIM];            // 64 KB
    for (int i = threadIdx.x; i < NEXP * DIM; i += 256) g[i] = gw[i];
    __syncthreads();
    const int wid = threadIdx.x >> 6, lane = threadIdx.x & 63;
    for (int it = 0; it < 8; ++it) {
        const int t = blockIdx.x * 32 + wid * 8 + it;
        float acc[NEXP];
#pragma unroll
        for (int e = 0; e < NEXP; ++e) acc[e] = 0.f;
        const float4* xr = (const float4*)(x + (size_t)t * DIM);
        for (int j = 0; j < DIM / 4; j += 64) {
            float4 xv = xr[j + lane];
#pragma unroll
            for (int e = 0; e < NEXP; ++e) {
                float4 gv = *(const float4*)&g[e * DIM + (j + lane) * 4];
                acc[e] += xv.x * gv.x + xv.y * gv.y + xv.z * gv.z + xv.w * gv.w;
            }
        }
#pragma unroll
        for (int e = 0; e < NEXP; ++e)
            for (int o = 32; o; o >>= 1) acc[e] += __shfl_xor(acc[e], o);
        if (lane == 0) {
            int e0 = 0; float v0 = acc[0];
#pragma unroll
            for (int e = 1; e < NEXP; ++e) if (acc[e] > v0) { v0 = acc[e]; e0 = e; }
            int e1 = -1; float v1 = -3.4e38f;
#pragma unroll
            for (int e = 0; e < NEXP; ++e) if (e != e0 && acc[e] > v1) { v1 = acc[e]; e1 = e; }
            float p0 = 1.f / (1.f + __expf(v1 - v0));   // softmax of [v0,v1], v0 >= v1
            float p1 = 1.f - p0;
            sel[2 * t] = e0; sel[2 * t + 1] = e1;
            atomicAdd(&s_e[e0], p0); atomicAdd(&s_e[e1], p1);
            atomicAdd(&meta[e0], 1); atomicAdd(&meta[e1], 1);
        }
    }
}

__global__ void scan_kernel(int* meta) {
    if (threadIdx.x == 0) {
        int acc = 0;
        for (int e = 0; e < NEXP; ++e) {
            meta[16 + e] = acc;   // offset
            meta[8 + e]  = acc;   // cursor
            acc += meta[e];
        }
        meta[24] = acc;
    }
}

__global__ __launch_bounds__(256) void fill_kernel(
    const int* __restrict__ sel, int* __restrict__ meta, int* __restrict__ list)
{
    const int t = blockIdx.x * 256 + threadIdx.x;
    int e0 = sel[2 * t], e1 = sel[2 * t + 1];
    int p0 = atomicAdd(&meta[8 + e0], 1); list[p0] = t;
    int p1 = atomicAdd(&meta[8 + e1], 1); list[p1] = t;
}

// ---- fused gate+up GEMM: act = silu(X @ W1^T) * (X @ W3^T), bf16 out -------
template<int N, bool GATHER>
__global__ __launch_bounds__(256) void mlp_up_kernel(
    const float* __restrict__ X,
    const float* __restrict__ W1g,
    const float* __restrict__ W3g,
    __hip_bfloat16* __restrict__ act,
    const int* __restrict__ list,
    const int* __restrict__ meta)
{
    constexpr int K = DIM;
    const int e = blockIdx.z;
    int count, base;
    if (GATHER) {
        count = meta[e]; base = meta[16 + e];
        if ((int)blockIdx.y * 128 >= count) return;
    } else { count = T_TOK; base = 0; }
    const float* __restrict__ B1 = W1g + (size_t)e * N * K;
    const float* __restrict__ B3 = W3g + (size_t)e * N * K;
    const int m0 = blockIdx.y * 128, n0 = blockIdx.x * 128;

    __shared__ alignas(16) short As[128 * 64];
    __shared__ alignas(16) short Bs1[128 * 64];
    __shared__ alignas(16) short Bs3[128 * 64];

    const int tid = threadIdx.x;
    const int srow = tid >> 3;          // 0..31 (x4 passes)
    const int sslot = tid & 7;          // 16B chunk within 64-col row
    const int scol = sslot * 8;

    int arow[4];
#pragma unroll
    for (int p = 0; p < 4; ++p) {
        int r = m0 + srow + 32 * p;
        if (r > count - 1) r = count - 1;
        arow[p] = GATHER ? list[base + r] : r;
    }

    const int wid = tid >> 6, lane = tid & 63;
    const int wm = (wid >> 1) * 64, wn = (wid & 1) * 64;
    const int l15 = lane & 15, lhi = lane >> 4;

    f32x4 accg[4][4], accu[4][4];
#pragma unroll
    for (int i = 0; i < 4; ++i)
#pragma unroll
        for (int j = 0; j < 4; ++j) { accg[i][j] = 0.f; accu[i][j] = 0.f; }

    for (int k0 = 0; k0 < K; k0 += 64) {
        __syncthreads();
#pragma unroll
        for (int p = 0; p < 4; ++p) {
            const int r = srow + 32 * p;
            const int wb = r * 128 + ((sslot ^ (r & 7)) << 4);
            {
                const float* s = X + (size_t)arow[p] * K + k0 + scol;
                float4 f0 = *(const float4*)s, f1 = *(const float4*)(s + 4);
                *(bfrag*)((char*)As + wb) = cvt8(f0, f1);
            }
            {
                const float* s = B1 + (size_t)(n0 + r) * K + k0 + scol;
                float4 f0 = *(const float4*)s, f1 = *(const float4*)(s + 4);
                *(bfrag*)((char*)Bs1 + wb) = cvt8(f0, f1);
            }
            {
                const float* s = B3 + (size_t)(n0 + r) * K + k0 + scol;
                float4 f0 = *(const float4*)s, f1 = *(const float4*)(s + 4);
                *(bfrag*)((char*)Bs3 + wb) = cvt8(f0, f1);
            }
        }
        __syncthreads();
#pragma unroll
        for (int kk = 0; kk < 2; ++kk) {
            bfrag af[4], b1f[4], b3f[4];
            const int c = kk * 4 + lhi;
#pragma unroll
            for (int i = 0; i < 4; ++i) {
                int ra = wm + i * 16 + l15;
                af[i] = *(const bfrag*)((const char*)As + ra * 128 + ((c ^ (ra & 7)) << 4));
                int rb = wn + i * 16 + l15;
                b1f[i] = *(const bfrag*)((const char*)Bs1 + rb * 128 + ((c ^ (rb & 7)) << 4));
                b3f[i] = *(const bfrag*)((const char*)Bs3 + rb * 128 + ((c ^ (rb & 7)) << 4));
            }
#pragma unroll
            for (int i = 0; i < 4; ++i)
#pragma unroll
                for (int j = 0; j < 4; ++j) {
                    accg[i][j] = __builtin_amdgcn_mfma_f32_16x16x32_bf16(af[i], b1f[j], accg[i][j], 0, 0, 0);
                    accu[i][j] = __builtin_amdgcn_mfma_f32_16x16x32_bf16(af[i], b3f[j], accu[i][j], 0, 0, 0);
                }
        }
    }
#pragma unroll
    for (int i = 0; i < 4; ++i) {
#pragma unroll
        for (int r = 0; r < 4; ++r) {
            int m = wm + i * 16 + lhi * 4 + r;
            if (m0 + m < count) {
#pragma unroll
                for (int j = 0; j < 4; ++j) {
                    float gg = accg[i][j][r];
                    float uu = accu[i][j][r];
                    float a = gg / (1.f + __expf(-gg)) * uu;   // silu(g)*u
                    int n = n0 + wn + j * 16 + l15;
                    act[(size_t)(base + m0 + m) * N + n] = __float2bfloat16(a);
                }
            }
        }
    }
}

// ---- down GEMM: out[t] (+)= scale * (A @ W2^T) --------------------------------
template<int K, bool SCATTER>
__global__ __launch_bounds__(256) void mlp_down_kernel(
    const __hip_bfloat16* __restrict__ A,
    const float* __restrict__ W2g,
    float* __restrict__ out,
    const int* __restrict__ list,
    const int* __restrict__ meta,
    const float* __restrict__ s_e)
{
    constexpr int N = DIM;
    const int e = blockIdx.z;
    int count, base;
    if (SCATTER) {
        count = meta[e]; base = meta[16 + e];
        if ((int)blockIdx.y * 128 >= count) return;
    } else { count = T_TOK; base = 0; }
    const float* __restrict__ B = W2g + (size_t)e * (size_t)N * K;
    const int m0 = blockIdx.y * 128, n0 = blockIdx.x * 128;

    __shared__ alignas(16) short As[128 * 64];
    __shared__ alignas(16) short Bs[128 * 64];
    __shared__ int tok_s[128];

    const int tid = threadIdx.x;
    if (SCATTER && tid < 128) {
        int r = m0 + tid; if (r > count - 1) r = count - 1;
        tok_s[tid] = list[base + r];
    }
    const int srow = tid >> 3, sslot = tid & 7;
    const int scol = sslot * 8;
    int arow[4];
#pragma unroll
    for (int p = 0; p < 4; ++p) {
        int r = m0 + srow + 32 * p;
        if (r > count - 1) r = count - 1;
        arow[p] = base + r;
    }

    const int wid = tid >> 6, lane = tid & 63;
    const int wm = (wid >> 1) * 64, wn = (wid & 1) * 64;
    const int l15 = lane & 15, lhi = lane >> 4;

    f32x4 acc[4][4];
#pragma unroll
    for (int i = 0; i < 4; ++i)
#pragma unroll
        for (int j = 0; j < 4; ++j) acc[i][j] = 0.f;

    for (int k0 = 0; k0 < K; k0 += 64) {
        __syncthreads();
#pragma unroll
        for (int p = 0; p < 4; ++p) {
            const int r = srow + 32 * p;
            const int wb = r * 128 + ((sslot ^ (r & 7)) << 4);
            {
                bfrag v = *(const bfrag*)(A + (size_t)arow[p] * K + k0 + scol);
                *(bfrag*)((char*)As + wb) = v;
            }
            {
                const float* s = B + (size_t)(n0 + r) * K + k0 + scol;
                float4 f0 = *(const float4*)s, f1 = *(const float4*)(s + 4);
                *(bfrag*)((char*)Bs + wb) = cvt8(f0, f1);
            }
        }
        __syncthreads();
#pragma unroll
        for (int kk = 0; kk < 2; ++kk) {
            bfrag af[4], bf[4];
            const int c = kk * 4 + lhi;
#pragma unroll
            for (int i = 0; i < 4; ++i) {
                int ra = wm + i * 16 + l15;
                af[i] = *(const bfrag*)((const char*)As + ra * 128 + ((c ^ (ra & 7)) << 4));
                int rb = wn + i * 16 + l15;
                bf[i] = *(const bfrag*)((const char*)Bs + rb * 128 + ((c ^ (rb & 7)) << 4));
            }
#pragma unroll
            for (int i = 0; i < 4; ++i)
#pragma unroll
                for (int j = 0; j < 4; ++j)
                    acc[i][j] = __builtin_amdgcn_mfma_f32_16x16x32_bf16(af[i], bf[j], acc[i][j], 0, 0, 0);
        }
    }
    const float scale = SCATTER ? s_e[e] : 1.0f;
#pragma unroll
    for (int i = 0; i < 4; ++i) {
#pragma unroll
        for (int r = 0; r < 4; ++r) {
            int m = wm + i * 16 + lhi * 4 + r;
            if (m0 + m < count) {
#pragma unroll
                for (int j = 0; j < 4; ++j) {
                    int n = n0 + wn + j * 16 + l15;
                    float v = acc[i][j][r] * scale;
                    if (SCATTER) atomicAdd(&out[(size_t)tok_s[m] * DIM + n], v);
                    else         out[(size_t)(m0 + m) * DIM + n] = v;
                }
            }
        }
    }
}

extern "C" void kernel_launch(void* const* d_in, const int* in_sizes, int n_in,
                              void* d_out, int out_size, void* d_ws, size_t ws_size,
                              hipStream_t stream) {
    const float* x   = (const float*)d_in[0];
    const float* gw  = (const float*)d_in[1];
    const float* w1  = (const float*)d_in[2];
    const float* w3  = (const float*)d_in[3];
    const float* w2  = (const float*)d_in[4];
    const float* sw1 = (const float*)d_in[5];
    const float* sw3 = (const float*)d_in[6];
    const float* sw2 = (const float*)d_in[7];
    float* out = (float*)d_out;

    // ws layout: act (46.1 MB, reused shared->expert) | list | sel | meta(256B)
    const size_t act_bytes = (size_t)2 * T_TOK * HDIM * sizeof(__hip_bfloat16); // == T*SHDIM*2
    char* p = (char*)d_ws;
    __hip_bfloat16* act = (__hip_bfloat16*)p; p += act_bytes;
    int* list = (int*)p; p += (size_t)2 * T_TOK * sizeof(int);
    int* sel  = (int*)p; p += (size_t)2 * T_TOK * sizeof(int);
    int* meta = (int*)p; p += 256;
    float* s_e = (float*)(meta + 32);
    if ((size_t)(p - (char*)d_ws) > ws_size) return;  // insufficient scratch

    hipMemsetAsync(meta, 0, 256, stream);
    gate_kernel<<<T_TOK / 32, 256, 0, stream>>>(x, gw, sel, meta, s_e);
    scan_kernel<<<1, 64, 0, stream>>>(meta);
    fill_kernel<<<T_TOK / 256, 256, 0, stream>>>(sel, meta, list);

    // shared expert first (plain-stores initialize out), then sparse experts add
    mlp_up_kernel<SHDIM, false><<<dim3(SHDIM / 128, T_TOK / 128, 1), 256, 0, stream>>>(
        x, sw1, sw3, act, nullptr, meta);
    mlp_down_kernel<SHDIM, false><<<dim3(DIM / 128, T_TOK / 128, 1), 256, 0, stream>>>(
        act, sw2, out, nullptr, meta, s_e);
    mlp_up_kernel<HDIM, true><<<dim3(HDIM / 128, T_TOK / 128, NEXP), 256, 0, stream>>>(
        x, w1, w3, act, list, meta);
    mlp_down_kernel<HDIM, true><<<dim3(DIM / 128, T_TOK / 128, NEXP), 256, 0, stream>>>(
        act, w2, out, list, meta, s_e);
}

// Round 2
// 1413.174 us; speedup vs baseline: 1.2856x; 1.2856x over previous
//
#include <hip/hip_runtime.h>
#include <hip/hip_bf16.h>
#include <stdint.h>

#define T_TOK 8192
#define DIM   2048
#define NEXP  8
#define HDIM  1408
#define SHDIM 2816

typedef __attribute__((ext_vector_type(8))) short bfrag;   // 8 x bf16 (4 VGPR)
typedef __attribute__((ext_vector_type(4))) float f32x4;

__device__ __forceinline__ short f2bf(float f) {
    union { float f; uint32_t u; } v; v.f = f;
    return (short)((v.u + 0x8000u) >> 16);   // round-half-up bf16
}

__device__ __forceinline__ bfrag cvt8(float4 a, float4 b) {
    bfrag r;
    r[0] = f2bf(a.x); r[1] = f2bf(a.y); r[2] = f2bf(a.z); r[3] = f2bf(a.w);
    r[4] = f2bf(b.x); r[5] = f2bf(b.y); r[6] = f2bf(b.z); r[7] = f2bf(b.w);
    return r;
}

__device__ __forceinline__ void gload16(const void* g, void* l) {
    __builtin_amdgcn_global_load_lds(
        (__attribute__((address_space(1))) void*)(g),
        (__attribute__((address_space(3))) void*)(l), 16, 0, 0);
}

// meta layout (ints): [0..7] counts, [8..15] cursor, [16..24] offsets, floats at +32: s_e[8]

__global__ __launch_bounds__(256) void gate_kernel(
    const float* __restrict__ x, const float* __restrict__ gw,
    int* __restrict__ sel, int* __restrict__ meta, float* __restrict__ s_e)
{
    __shared__ float g[NEXP * DIM];            // 64 KB
    for (int i = threadIdx.x; i < NEXP * DIM; i += 256) g[i] = gw[i];
    __syncthreads();
    const int wid = threadIdx.x >> 6, lane = threadIdx.x & 63;
    for (int it = 0; it < 8; ++it) {
        const int t = blockIdx.x * 32 + wid * 8 + it;
        float acc[NEXP];
#pragma unroll
        for (int e = 0; e < NEXP; ++e) acc[e] = 0.f;
        const float4* xr = (const float4*)(x + (size_t)t * DIM);
        for (int j = 0; j < DIM / 4; j += 64) {
            float4 xv = xr[j + lane];
#pragma unroll
            for (int e = 0; e < NEXP; ++e) {
                float4 gv = *(const float4*)&g[e * DIM + (j + lane) * 4];
                acc[e] += xv.x * gv.x + xv.y * gv.y + xv.z * gv.z + xv.w * gv.w;
            }
        }
#pragma unroll
        for (int e = 0; e < NEXP; ++e)
            for (int o = 32; o; o >>= 1) acc[e] += __shfl_xor(acc[e], o);
        if (lane == 0) {
            int e0 = 0; float v0 = acc[0];
#pragma unroll
            for (int e = 1; e < NEXP; ++e) if (acc[e] > v0) { v0 = acc[e]; e0 = e; }
            int e1 = -1; float v1 = -3.4e38f;
#pragma unroll
            for (int e = 0; e < NEXP; ++e) if (e != e0 && acc[e] > v1) { v1 = acc[e]; e1 = e; }
            float p0 = 1.f / (1.f + __expf(v1 - v0));   // softmax of [v0,v1], v0 >= v1
            float p1 = 1.f - p0;
            sel[2 * t] = e0; sel[2 * t + 1] = e1;
            atomicAdd(&s_e[e0], p0); atomicAdd(&s_e[e1], p1);
            atomicAdd(&meta[e0], 1); atomicAdd(&meta[e1], 1);
        }
    }
}

__global__ void scan_kernel(int* meta) {
    if (threadIdx.x == 0) {
        int acc = 0;
        for (int e = 0; e < NEXP; ++e) {
            meta[16 + e] = acc;   // offset
            meta[8 + e]  = acc;   // cursor
            acc += meta[e];
        }
        meta[24] = acc;
    }
}

__global__ __launch_bounds__(256) void fill_kernel(
    const int* __restrict__ sel, int* __restrict__ meta, int* __restrict__ list)
{
    const int t = blockIdx.x * 256 + threadIdx.x;
    int e0 = sel[2 * t], e1 = sel[2 * t + 1];
    int p0 = atomicAdd(&meta[8 + e0], 1); list[p0] = t;
    int p1 = atomicAdd(&meta[8 + e1], 1); list[p1] = t;
}

__global__ __launch_bounds__(256) void cvt_kernel(
    const float* __restrict__ in, __hip_bfloat16* __restrict__ out, int n8)
{
    int i = blockIdx.x * 256 + threadIdx.x;
    const int stride = gridDim.x * 256;
    for (; i < n8; i += stride) {
        const float4* p = (const float4*)(in + (size_t)i * 8);
        float4 a = p[0], b = p[1];
        *(bfrag*)(out + (size_t)i * 8) = cvt8(a, b);
    }
}

// ============ v2 path: all-bf16 GEMMs with global_load_lds staging ============
// LDS tile layout: [128 rows][64 bf16] linear, with XOR swizzle applied by
// pre-swizzling the per-lane GLOBAL source column-slot (rule 21: linear dest +
// inverse-swz source + swz read).

// fused gate+up: act = silu(X@W1^T) * (X@W3^T), bf16 out
template<int N, bool GATHER>
__global__ __launch_bounds__(256) void up_v2(
    const __hip_bfloat16* __restrict__ X,    // [T,DIM]
    const __hip_bfloat16* __restrict__ W1,   // [E][N][DIM]
    const __hip_bfloat16* __restrict__ W3,
    __hip_bfloat16* __restrict__ act,        // [rows][N]
    const int* __restrict__ list,
    const int* __restrict__ meta)
{
    constexpr int K = DIM;
    constexpr int nx = N / 128, ny = T_TOK / 128, nz = GATHER ? NEXP : 1;
    constexpr int nwg = nx * ny * nz, cpx = nwg / 8;
    // XCD-chunked swizzle: consecutive virt ids (same m-row, different n) land
    // on the same XCD -> A-tile L2 reuse.
    const int bid = (int)blockIdx.x + nx * ((int)blockIdx.y + ny * (int)blockIdx.z);
    const int virt = (bid & 7) * cpx + (bid >> 3);
    const int xi = virt % nx;
    const int rest = virt / nx;
    const int yi = rest % ny;
    const int e = rest / ny;

    int count, base;
    if (GATHER) {
        count = meta[e]; base = meta[16 + e];
        if (yi * 128 >= count) return;
    } else { count = T_TOK; base = 0; }
    const int m0 = yi * 128, n0 = xi * 128;

    __shared__ alignas(16) short As[128 * 64];
    __shared__ alignas(16) short Bs1[128 * 64];
    __shared__ alignas(16) short Bs3[128 * 64];

    const int tid = threadIdx.x, wid = tid >> 6, lane = tid & 63;
    const int rhi = lane >> 3;                 // row&7 within chunk
    const int swslot = (lane & 7) ^ rhi;       // pre-swizzled source 16B slot

    const __hip_bfloat16* pA[4];
    const __hip_bfloat16* pB1[4];
    const __hip_bfloat16* pB3[4];
    short* dA[4]; short* dB1[4]; short* dB3[4];
#pragma unroll
    for (int q = 0; q < 4; ++q) {
        const int c = wid * 4 + q;             // 1KB chunk id, rows 8c..8c+7
        const int row = 8 * c + rhi;
        int r = m0 + row; if (r > count - 1) r = count - 1;
        const int ga = GATHER ? list[base + r] : r;
        pA[q]  = X  + (size_t)ga * K + swslot * 8;
        pB1[q] = W1 + ((size_t)e * N + n0 + row) * K + swslot * 8;
        pB3[q] = W3 + ((size_t)e * N + n0 + row) * K + swslot * 8;
        dA[q]  = As  + c * 512;
        dB1[q] = Bs1 + c * 512;
        dB3[q] = Bs3 + c * 512;
    }

    const int wm = (wid >> 1) * 64, wn = (wid & 1) * 64;
    const int l15 = lane & 15, lhi = lane >> 4;

    f32x4 accg[4][4], accu[4][4];
#pragma unroll
    for (int i = 0; i < 4; ++i)
#pragma unroll
        for (int j = 0; j < 4; ++j) { accg[i][j] = 0.f; accu[i][j] = 0.f; }

    for (int k0 = 0; k0 < K; k0 += 64) {
        __syncthreads();
#pragma unroll
        for (int q = 0; q < 4; ++q) gload16(pA[q] + k0, dA[q]);
#pragma unroll
        for (int q = 0; q < 4; ++q) gload16(pB1[q] + k0, dB1[q]);
#pragma unroll
        for (int q = 0; q < 4; ++q) gload16(pB3[q] + k0, dB3[q]);
        __syncthreads();   // compiler drains vmcnt before barrier (m97)
#pragma unroll
        for (int kk = 0; kk < 2; ++kk) {
            bfrag af[4], b1f[4], b3f[4];
            const int c = kk * 4 + lhi;
#pragma unroll
            for (int i = 0; i < 4; ++i) {
                int ra = wm + i * 16 + l15;
                af[i] = *(const bfrag*)((const char*)As + ra * 128 + ((c ^ (ra & 7)) << 4));
                int rb = wn + i * 16 + l15;
                b1f[i] = *(const bfrag*)((const char*)Bs1 + rb * 128 + ((c ^ (rb & 7)) << 4));
                b3f[i] = *(const bfrag*)((const char*)Bs3 + rb * 128 + ((c ^ (rb & 7)) << 4));
            }
#pragma unroll
            for (int i = 0; i < 4; ++i)
#pragma unroll
                for (int j = 0; j < 4; ++j) {
                    accg[i][j] = __builtin_amdgcn_mfma_f32_16x16x32_bf16(af[i], b1f[j], accg[i][j], 0, 0, 0);
                    accu[i][j] = __builtin_amdgcn_mfma_f32_16x16x32_bf16(af[i], b3f[j], accu[i][j], 0, 0, 0);
                }
        }
    }
#pragma unroll
    for (int i = 0; i < 4; ++i) {
#pragma unroll
        for (int r = 0; r < 4; ++r) {
            int m = wm + i * 16 + lhi * 4 + r;
            if (m0 + m < count) {
#pragma unroll
                for (int j = 0; j < 4; ++j) {
                    float gg = accg[i][j][r];
                    float uu = accu[i][j][r];
                    float a = gg / (1.f + __expf(-gg)) * uu;   // silu(g)*u
                    int n = n0 + wn + j * 16 + l15;
                    act[(size_t)(base + m0 + m) * N + n] = __float2bfloat16(a);
                }
            }
        }
    }
}

// down: out[t] (+)= scale * (A @ W2^T)
template<int K, bool SCATTER>
__global__ __launch_bounds__(256) void down_v2(
    const __hip_bfloat16* __restrict__ A,     // act [rows][K]
    const __hip_bfloat16* __restrict__ W2,    // [E][DIM][K]
    float* __restrict__ out,
    const int* __restrict__ list,
    const int* __restrict__ meta,
    const float* __restrict__ s_e)
{
    constexpr int N = DIM;
    constexpr int nx = N / 128, ny = T_TOK / 128, nz = SCATTER ? NEXP : 1;
    constexpr int nwg = nx * ny * nz, cpx = nwg / 8;
    const int bid = (int)blockIdx.x + nx * ((int)blockIdx.y + ny * (int)blockIdx.z);
    const int virt = (bid & 7) * cpx + (bid >> 3);
    const int xi = virt % nx;
    const int rest = virt / nx;
    const int yi = rest % ny;
    const int e = rest / ny;

    int count, base;
    if (SCATTER) {
        count = meta[e]; base = meta[16 + e];
        if (yi * 128 >= count) return;
    } else { count = T_TOK; base = 0; }
    const int m0 = yi * 128, n0 = xi * 128;

    __shared__ alignas(16) short As[128 * 64];
    __shared__ alignas(16) short Bs[128 * 64];
    __shared__ int tok_s[128];

    const int tid = threadIdx.x, wid = tid >> 6, lane = tid & 63;
    if (SCATTER && tid < 128) {
        int r = m0 + tid; if (r > count - 1) r = count - 1;
        tok_s[tid] = list[base + r];
    }
    const int rhi = lane >> 3;
    const int swslot = (lane & 7) ^ rhi;

    const __hip_bfloat16* pA[4];
    const __hip_bfloat16* pB[4];
    short* dA[4]; short* dB[4];
#pragma unroll
    for (int q = 0; q < 4; ++q) {
        const int c = wid * 4 + q;
        const int row = 8 * c + rhi;
        int r = m0 + row; if (r > count - 1) r = count - 1;
        pA[q] = A  + (size_t)(base + r) * K + swslot * 8;
        pB[q] = W2 + ((size_t)e * N + n0 + row) * K + swslot * 8;
        dA[q] = As + c * 512;
        dB[q] = Bs + c * 512;
    }

    const int wm = (wid >> 1) * 64, wn = (wid & 1) * 64;
    const int l15 = lane & 15, lhi = lane >> 4;

    f32x4 acc[4][4];
#pragma unroll
    for (int i = 0; i < 4; ++i)
#pragma unroll
        for (int j = 0; j < 4; ++j) acc[i][j] = 0.f;

    for (int k0 = 0; k0 < K; k0 += 64) {
        __syncthreads();
#pragma unroll
        for (int q = 0; q < 4; ++q) gload16(pA[q] + k0, dA[q]);
#pragma unroll
        for (int q = 0; q < 4; ++q) gload16(pB[q] + k0, dB[q]);
        __syncthreads();
#pragma unroll
        for (int kk = 0; kk < 2; ++kk) {
            bfrag af[4], bf[4];
            const int c = kk * 4 + lhi;
#pragma unroll
            for (int i = 0; i < 4; ++i) {
                int ra = wm + i * 16 + l15;
                af[i] = *(const bfrag*)((const char*)As + ra * 128 + ((c ^ (ra & 7)) << 4));
                int rb = wn + i * 16 + l15;
                bf[i] = *(const bfrag*)((const char*)Bs + rb * 128 + ((c ^ (rb & 7)) << 4));
            }
#pragma unroll
            for (int i = 0; i < 4; ++i)
#pragma unroll
                for (int j = 0; j < 4; ++j)
                    acc[i][j] = __builtin_amdgcn_mfma_f32_16x16x32_bf16(af[i], bf[j], acc[i][j], 0, 0, 0);
        }
    }
    const float scale = SCATTER ? s_e[e] : 1.0f;
#pragma unroll
    for (int i = 0; i < 4; ++i) {
#pragma unroll
        for (int r = 0; r < 4; ++r) {
            int m = wm + i * 16 + lhi * 4 + r;
            if (m0 + m < count) {
#pragma unroll
                for (int j = 0; j < 4; ++j) {
                    int n = n0 + wn + j * 16 + l15;
                    float v = acc[i][j][r] * scale;
                    if (SCATTER) atomicAdd(&out[(size_t)tok_s[m] * DIM + n], v);
                    else         out[(size_t)(m0 + m) * DIM + n] = v;
                }
            }
        }
    }
}

// ============ v1 fallback path (R1 kernels, fp32 reg-staged) ============

template<int N, bool GATHER>
__global__ __launch_bounds__(256) void mlp_up_kernel(
    const float* __restrict__ X,
    const float* __restrict__ W1g,
    const float* __restrict__ W3g,
    __hip_bfloat16* __restrict__ act,
    const int* __restrict__ list,
    const int* __restrict__ meta)
{
    constexpr int K = DIM;
    const int e = blockIdx.z;
    int count, base;
    if (GATHER) {
        count = meta[e]; base = meta[16 + e];
        if ((int)blockIdx.y * 128 >= count) return;
    } else { count = T_TOK; base = 0; }
    const float* __restrict__ B1 = W1g + (size_t)e * N * K;
    const float* __restrict__ B3 = W3g + (size_t)e * N * K;
    const int m0 = blockIdx.y * 128, n0 = blockIdx.x * 128;

    __shared__ alignas(16) short As[128 * 64];
    __shared__ alignas(16) short Bs1[128 * 64];
    __shared__ alignas(16) short Bs3[128 * 64];

    const int tid = threadIdx.x;
    const int srow = tid >> 3;
    const int sslot = tid & 7;
    const int scol = sslot * 8;

    int arow[4];
#pragma unroll
    for (int p = 0; p < 4; ++p) {
        int r = m0 + srow + 32 * p;
        if (r > count - 1) r = count - 1;
        arow[p] = GATHER ? list[base + r] : r;
    }

    const int wid = tid >> 6, lane = tid & 63;
    const int wm = (wid >> 1) * 64, wn = (wid & 1) * 64;
    const int l15 = lane & 15, lhi = lane >> 4;

    f32x4 accg[4][4], accu[4][4];
#pragma unroll
    for (int i = 0; i < 4; ++i)
#pragma unroll
        for (int j = 0; j < 4; ++j) { accg[i][j] = 0.f; accu[i][j] = 0.f; }

    for (int k0 = 0; k0 < K; k0 += 64) {
        __syncthreads();
#pragma unroll
        for (int p = 0; p < 4; ++p) {
            const int r = srow + 32 * p;
            const int wb = r * 128 + ((sslot ^ (r & 7)) << 4);
            {
                const float* s = X + (size_t)arow[p] * K + k0 + scol;
                float4 f0 = *(const float4*)s, f1 = *(const float4*)(s + 4);
                *(bfrag*)((char*)As + wb) = cvt8(f0, f1);
            }
            {
                const float* s = B1 + (size_t)(n0 + r) * K + k0 + scol;
                float4 f0 = *(const float4*)s, f1 = *(const float4*)(s + 4);
                *(bfrag*)((char*)Bs1 + wb) = cvt8(f0, f1);
            }
            {
                const float* s = B3 + (size_t)(n0 + r) * K + k0 + scol;
                float4 f0 = *(const float4*)s, f1 = *(const float4*)(s + 4);
                *(bfrag*)((char*)Bs3 + wb) = cvt8(f0, f1);
            }
        }
        __syncthreads();
#pragma unroll
        for (int kk = 0; kk < 2; ++kk) {
            bfrag af[4], b1f[4], b3f[4];
            const int c = kk * 4 + lhi;
#pragma unroll
            for (int i = 0; i < 4; ++i) {
                int ra = wm + i * 16 + l15;
                af[i] = *(const bfrag*)((const char*)As + ra * 128 + ((c ^ (ra & 7)) << 4));
                int rb = wn + i * 16 + l15;
                b1f[i] = *(const bfrag*)((const char*)Bs1 + rb * 128 + ((c ^ (rb & 7)) << 4));
                b3f[i] = *(const bfrag*)((const char*)Bs3 + rb * 128 + ((c ^ (rb & 7)) << 4));
            }
#pragma unroll
            for (int i = 0; i < 4; ++i)
#pragma unroll
                for (int j = 0; j < 4; ++j) {
                    accg[i][j] = __builtin_amdgcn_mfma_f32_16x16x32_bf16(af[i], b1f[j], accg[i][j], 0, 0, 0);
                    accu[i][j] = __builtin_amdgcn_mfma_f32_16x16x32_bf16(af[i], b3f[j], accu[i][j], 0, 0, 0);
                }
        }
    }
#pragma unroll
    for (int i = 0; i < 4; ++i) {
#pragma unroll
        for (int r = 0; r < 4; ++r) {
            int m = wm + i * 16 + lhi * 4 + r;
            if (m0 + m < count) {
#pragma unroll
                for (int j = 0; j < 4; ++j) {
                    float gg = accg[i][j][r];
                    float uu = accu[i][j][r];
                    float a = gg / (1.f + __expf(-gg)) * uu;
                    int n = n0 + wn + j * 16 + l15;
                    act[(size_t)(base + m0 + m) * N + n] = __float2bfloat16(a);
                }
            }
        }
    }
}

template<int K, bool SCATTER>
__global__ __launch_bounds__(256) void mlp_down_kernel(
    const __hip_bfloat16* __restrict__ A,
    const float* __restrict__ W2g,
    float* __restrict__ out,
    const int* __restrict__ list,
    const int* __restrict__ meta,
    const float* __restrict__ s_e)
{
    constexpr int N = DIM;
    const int e = blockIdx.z;
    int count, base;
    if (SCATTER) {
        count = meta[e]; base = meta[16 + e];
        if ((int)blockIdx.y * 128 >= count) return;
    } else { count = T_TOK; base = 0; }
    const float* __restrict__ B = W2g + (size_t)e * (size_t)N * K;
    const int m0 = blockIdx.y * 128, n0 = blockIdx.x * 128;

    __shared__ alignas(16) short As[128 * 64];
    __shared__ alignas(16) short Bs[128 * 64];
    __shared__ int tok_s[128];

    const int tid = threadIdx.x;
    if (SCATTER && tid < 128) {
        int r = m0 + tid; if (r > count - 1) r = count - 1;
        tok_s[tid] = list[base + r];
    }
    const int srow = tid >> 3, sslot = tid & 7;
    const int scol = sslot * 8;
    int arow[4];
#pragma unroll
    for (int p = 0; p < 4; ++p) {
        int r = m0 + srow + 32 * p;
        if (r > count - 1) r = count - 1;
        arow[p] = base + r;
    }

    const int wid = tid >> 6, lane = tid & 63;
    const int wm = (wid >> 1) * 64, wn = (wid & 1) * 64;
    const int l15 = lane & 15, lhi = lane >> 4;

    f32x4 acc[4][4];
#pragma unroll
    for (int i = 0; i < 4; ++i)
#pragma unroll
        for (int j = 0; j < 4; ++j) acc[i][j] = 0.f;

    for (int k0 = 0; k0 < K; k0 += 64) {
        __syncthreads();
#pragma unroll
        for (int p = 0; p < 4; ++p) {
            const int r = srow + 32 * p;
            const int wb = r * 128 + ((sslot ^ (r & 7)) << 4);
            {
                bfrag v = *(const bfrag*)(A + (size_t)arow[p] * K + k0 + scol);
                *(bfrag*)((char*)As + wb) = v;
            }
            {
                const float* s = B + (size_t)(n0 + r) * K + k0 + scol;
                float4 f0 = *(const float4*)s, f1 = *(const float4*)(s + 4);
                *(bfrag*)((char*)Bs + wb) = cvt8(f0, f1);
            }
        }
        __syncthreads();
#pragma unroll
        for (int kk = 0; kk < 2; ++kk) {
            bfrag af[4], bf[4];
            const int c = kk * 4 + lhi;
#pragma unroll
            for (int i = 0; i < 4; ++i) {
                int ra = wm + i * 16 + l15;
                af[i] = *(const bfrag*)((const char*)As + ra * 128 + ((c ^ (ra & 7)) << 4));
                int rb = wn + i * 16 + l15;
                bf[i] = *(const bfrag*)((const char*)Bs + rb * 128 + ((c ^ (rb & 7)) << 4));
            }
#pragma unroll
            for (int i = 0; i < 4; ++i)
#pragma unroll
                for (int j = 0; j < 4; ++j)
                    acc[i][j] = __builtin_amdgcn_mfma_f32_16x16x32_bf16(af[i], bf[j], acc[i][j], 0, 0, 0);
        }
    }
    const float scale = SCATTER ? s_e[e] : 1.0f;
#pragma unroll
    for (int i = 0; i < 4; ++i) {
#pragma unroll
        for (int r = 0; r < 4; ++r) {
            int m = wm + i * 16 + lhi * 4 + r;
            if (m0 + m < count) {
#pragma unroll
                for (int j = 0; j < 4; ++j) {
                    int n = n0 + wn + j * 16 + l15;
                    float v = acc[i][j][r] * scale;
                    if (SCATTER) atomicAdd(&out[(size_t)tok_s[m] * DIM + n], v);
                    else         out[(size_t)(m0 + m) * DIM + n] = v;
                }
            }
        }
    }
}

extern "C" void kernel_launch(void* const* d_in, const int* in_sizes, int n_in,
                              void* d_out, int out_size, void* d_ws, size_t ws_size,
                              hipStream_t stream) {
    const float* x   = (const float*)d_in[0];
    const float* gw  = (const float*)d_in[1];
    const float* w1  = (const float*)d_in[2];
    const float* w3  = (const float*)d_in[3];
    const float* w2  = (const float*)d_in[4];
    const float* sw1 = (const float*)d_in[5];
    const float* sw3 = (const float*)d_in[6];
    const float* sw2 = (const float*)d_in[7];
    float* out = (float*)d_out;

    // ---- Tier-A layout: all-bf16 copies ----
    const size_t SZ_X   = (size_t)T_TOK * DIM * 2;            // 32 MB
    const size_t SZ_W   = (size_t)NEXP * HDIM * DIM * 2;      // 46.1 MB (w1/w3/w2 each)
    const size_t SZ_SW  = (size_t)SHDIM * DIM * 2;            // 11.5 MB (sw1/sw3/sw2 each)
    const size_t SZ_ACT = (size_t)2 * T_TOK * HDIM * 2;       // 46.1 MB (== T*SHDIM*2)
    const size_t tierA = SZ_X + 3 * SZ_W + 3 * SZ_SW + SZ_ACT
                       + (size_t)4 * T_TOK * sizeof(int) + 512;

    if (tierA <= ws_size) {
        char* p = (char*)d_ws;
        __hip_bfloat16* xbf   = (__hip_bfloat16*)p; p += SZ_X;
        __hip_bfloat16* w1bf  = (__hip_bfloat16*)p; p += SZ_W;
        __hip_bfloat16* w3bf  = (__hip_bfloat16*)p; p += SZ_W;
        __hip_bfloat16* w2bf  = (__hip_bfloat16*)p; p += SZ_W;
        __hip_bfloat16* sw1bf = (__hip_bfloat16*)p; p += SZ_SW;
        __hip_bfloat16* sw3bf = (__hip_bfloat16*)p; p += SZ_SW;
        __hip_bfloat16* sw2bf = (__hip_bfloat16*)p; p += SZ_SW;
        __hip_bfloat16* act   = (__hip_bfloat16*)p; p += SZ_ACT;
        int* list = (int*)p; p += (size_t)2 * T_TOK * sizeof(int);
        int* sel  = (int*)p; p += (size_t)2 * T_TOK * sizeof(int);
        int* meta = (int*)p;
        float* s_e = (float*)(meta + 32);

        hipMemsetAsync(meta, 0, 256, stream);
        gate_kernel<<<T_TOK / 32, 256, 0, stream>>>(x, gw, sel, meta, s_e);
        scan_kernel<<<1, 64, 0, stream>>>(meta);
        fill_kernel<<<T_TOK / 256, 256, 0, stream>>>(sel, meta, list);

        cvt_kernel<<<2048, 256, 0, stream>>>(x,   xbf,   T_TOK * DIM / 8);
        cvt_kernel<<<2048, 256, 0, stream>>>(w1,  w1bf,  NEXP * HDIM * DIM / 8);
        cvt_kernel<<<2048, 256, 0, stream>>>(w3,  w3bf,  NEXP * HDIM * DIM / 8);
        cvt_kernel<<<2048, 256, 0, stream>>>(w2,  w2bf,  NEXP * HDIM * DIM / 8);
        cvt_kernel<<<2048, 256, 0, stream>>>(sw1, sw1bf, SHDIM * DIM / 8);
        cvt_kernel<<<2048, 256, 0, stream>>>(sw3, sw3bf, SHDIM * DIM / 8);
        cvt_kernel<<<2048, 256, 0, stream>>>(sw2, sw2bf, SHDIM * DIM / 8);

        // shared expert first (plain stores init out), then sparse experts add
        up_v2<SHDIM, false><<<dim3(SHDIM / 128, T_TOK / 128, 1), 256, 0, stream>>>(
            xbf, sw1bf, sw3bf, act, nullptr, meta);
        down_v2<SHDIM, false><<<dim3(DIM / 128, T_TOK / 128, 1), 256, 0, stream>>>(
            act, sw2bf, out, nullptr, meta, s_e);
        up_v2<HDIM, true><<<dim3(HDIM / 128, T_TOK / 128, NEXP), 256, 0, stream>>>(
            xbf, w1bf, w3bf, act, list, meta);
        down_v2<HDIM, true><<<dim3(DIM / 128, T_TOK / 128, NEXP), 256, 0, stream>>>(
            act, w2bf, out, list, meta, s_e);
        return;
    }

    // ---- fallback: R1 path ----
    const size_t act_bytes = (size_t)2 * T_TOK * HDIM * sizeof(__hip_bfloat16);
    char* p = (char*)d_ws;
    __hip_bfloat16* act = (__hip_bfloat16*)p; p += act_bytes;
    int* list = (int*)p; p += (size_t)2 * T_TOK * sizeof(int);
    int* sel  = (int*)p; p += (size_t)2 * T_TOK * sizeof(int);
    int* meta = (int*)p; p += 256;
    float* s_e = (float*)(meta + 32);
    if ((size_t)(p - (char*)d_ws) > ws_size) return;

    hipMemsetAsync(meta, 0, 256, stream);
    gate_kernel<<<T_TOK / 32, 256, 0, stream>>>(x, gw, sel, meta, s_e);
    scan_kernel<<<1, 64, 0, stream>>>(meta);
    fill_kernel<<<T_TOK / 256, 256, 0, stream>>>(sel, meta, list);

    mlp_up_kernel<SHDIM, false><<<dim3(SHDIM / 128, T_TOK / 128, 1), 256, 0, stream>>>(
        x, sw1, sw3, act, nullptr, meta);
    mlp_down_kernel<SHDIM, false><<<dim3(DIM / 128, T_TOK / 128, 1), 256, 0, stream>>>(
        act, sw2, out, nullptr, meta, s_e);
    mlp_up_kernel<HDIM, true><<<dim3(HDIM / 128, T_TOK / 128, NEXP), 256, 0, stream>>>(
        x, w1, w3, act, list, meta);
    mlp_down_kernel<HDIM, true><<<dim3(DIM / 128, T_TOK / 128, NEXP), 256, 0, stream>>>(
        act, w2, out, list, meta, s_e);
}

// Round 3
// 1180.719 us; speedup vs baseline: 1.5387x; 1.1969x over previous
//
#include <hip/hip_runtime.h>
#include <hip/hip_bf16.h>
#include <stdint.h>

#define T_TOK 8192
#define DIM   2048
#define NEXP  8
#define HDIM  1408
#define SHDIM 2816

typedef __attribute__((ext_vector_type(8))) short bfrag;   // 8 x bf16 (4 VGPR)
typedef __attribute__((ext_vector_type(4))) float f32x4;

__device__ __forceinline__ short f2bf(float f) {
    union { float f; uint32_t u; } v; v.f = f;
    return (short)((v.u + 0x8000u) >> 16);   // round-half-up bf16
}

__device__ __forceinline__ bfrag cvt8(float4 a, float4 b) {
    bfrag r;
    r[0] = f2bf(a.x); r[1] = f2bf(a.y); r[2] = f2bf(a.z); r[3] = f2bf(a.w);
    r[4] = f2bf(b.x); r[5] = f2bf(b.y); r[6] = f2bf(b.z); r[7] = f2bf(b.w);
    return r;
}

__device__ __forceinline__ void gload16(const void* g, void* l) {
    __builtin_amdgcn_global_load_lds(
        (__attribute__((address_space(1))) void*)(g),
        (__attribute__((address_space(3))) void*)(l), 16, 0, 0);
}

#define MFMA16(a, b, c) __builtin_amdgcn_mfma_f32_16x16x32_bf16((a), (b), (c), 0, 0, 0)

// meta layout (ints): [0..7] counts, [8..15] cursor, [16..24] offsets, floats at +32: s_e[8]

__global__ __launch_bounds__(256) void gate_kernel(
    const float* __restrict__ x, const float* __restrict__ gw,
    int* __restrict__ sel, int* __restrict__ meta, float* __restrict__ s_e)
{
    __shared__ float g[NEXP * DIM];            // 64 KB
    for (int i = threadIdx.x; i < NEXP * DIM; i += 256) g[i] = gw[i];
    __syncthreads();
    const int wid = threadIdx.x >> 6, lane = threadIdx.x & 63;
    for (int it = 0; it < 8; ++it) {
        const int t = blockIdx.x * 32 + wid * 8 + it;
        float acc[NEXP];
#pragma unroll
        for (int e = 0; e < NEXP; ++e) acc[e] = 0.f;
        const float4* xr = (const float4*)(x + (size_t)t * DIM);
        for (int j = 0; j < DIM / 4; j += 64) {
            float4 xv = xr[j + lane];
#pragma unroll
            for (int e = 0; e < NEXP; ++e) {
                float4 gv = *(const float4*)&g[e * DIM + (j + lane) * 4];
                acc[e] += xv.x * gv.x + xv.y * gv.y + xv.z * gv.z + xv.w * gv.w;
            }
        }
#pragma unroll
        for (int e = 0; e < NEXP; ++e)
            for (int o = 32; o; o >>= 1) acc[e] += __shfl_xor(acc[e], o);
        if (lane == 0) {
            int e0 = 0; float v0 = acc[0];
#pragma unroll
            for (int e = 1; e < NEXP; ++e) if (acc[e] > v0) { v0 = acc[e]; e0 = e; }
            int e1 = -1; float v1 = -3.4e38f;
#pragma unroll
            for (int e = 0; e < NEXP; ++e) if (e != e0 && acc[e] > v1) { v1 = acc[e]; e1 = e; }
            float p0 = 1.f / (1.f + __expf(v1 - v0));   // softmax of [v0,v1], v0 >= v1
            float p1 = 1.f - p0;
            sel[2 * t] = e0; sel[2 * t + 1] = e1;
            atomicAdd(&s_e[e0], p0); atomicAdd(&s_e[e1], p1);
            atomicAdd(&meta[e0], 1); atomicAdd(&meta[e1], 1);
        }
    }
}

__global__ void scan_kernel(int* meta) {
    if (threadIdx.x == 0) {
        int acc = 0;
        for (int e = 0; e < NEXP; ++e) {
            meta[16 + e] = acc;   // offset
            meta[8 + e]  = acc;   // cursor
            acc += meta[e];
        }
        meta[24] = acc;
    }
}

__global__ __launch_bounds__(256) void fill_kernel(
    const int* __restrict__ sel, int* __restrict__ meta, int* __restrict__ list)
{
    const int t = blockIdx.x * 256 + threadIdx.x;
    int e0 = sel[2 * t], e1 = sel[2 * t + 1];
    int p0 = atomicAdd(&meta[8 + e0], 1); list[p0] = t;
    int p1 = atomicAdd(&meta[8 + e1], 1); list[p1] = t;
}

__global__ __launch_bounds__(256) void cvt_kernel(
    const float* __restrict__ in, __hip_bfloat16* __restrict__ out, int n8)
{
    int i = blockIdx.x * 256 + threadIdx.x;
    const int stride = gridDim.x * 256;
    for (; i < n8; i += stride) {
        const float4* p = (const float4*)(in + (size_t)i * 8);
        float4 a = p[0], b = p[1];
        *(bfrag*)(out + (size_t)i * 8) = cvt8(a, b);
    }
}

// ===================== 2-phase double-buffered MFMA GEMMs =====================
// Structure (T3-minimum, proven m230-V0): per K-tile, issue next tile's
// global_load_lds into buf^1 FIRST, then ds_read+MFMA current buf, then one
// __syncthreads (compiler drains vmcnt before s_barrier -> next tile landed).
// LDS: linear dest + inverse-swizzled global source + swizzled ds_read (rule 21).

// fused gate+up: act = silu(X@W1^T) * (X@W3^T), bf16 out. BM=256, BN=128, BK=64.
template<int N, bool GATHER>
__global__ __launch_bounds__(512, 2) void up_v3(
    const __hip_bfloat16* __restrict__ X,    // [T,DIM]
    const __hip_bfloat16* __restrict__ W1,   // [E][N][DIM]
    const __hip_bfloat16* __restrict__ W3,
    __hip_bfloat16* __restrict__ act,        // [rows][N]
    const int* __restrict__ list,
    const int* __restrict__ meta)
{
    constexpr int K = DIM;
    constexpr int NT = K / 64;
    constexpr int nx = N / 128, ny = T_TOK / 256, nz = GATHER ? NEXP : 1;
    constexpr int nwg = nx * ny * nz, cpx = nwg / 8;
    const int bid = (int)blockIdx.x + nx * ((int)blockIdx.y + ny * (int)blockIdx.z);
    const int virt = (bid & 7) * cpx + (bid >> 3);
    const int xi = virt % nx;
    const int rest = virt / nx;
    const int yi = rest % ny;
    const int e = rest / ny;

    int count, base;
    if (GATHER) {
        count = meta[e]; base = meta[16 + e];
        if (yi * 256 >= count) return;
    } else { count = T_TOK; base = 0; }
    const int m0 = yi * 256, n0 = xi * 128;

    __shared__ alignas(16) short As[2][256 * 64];    // 64 KB
    __shared__ alignas(16) short B1s[2][128 * 64];   // 32 KB
    __shared__ alignas(16) short B3s[2][128 * 64];   // 32 KB

    const int tid = threadIdx.x, wid = tid >> 6, lane = tid & 63;
    const int rlo = lane >> 3;               // row within 8-row chunk
    const int swslot = (lane & 7) ^ rlo;     // pre-swizzled source 16B slot

    const __hip_bfloat16* pA[4];
#pragma unroll
    for (int q = 0; q < 4; ++q) {
        int row = (q * 8 + wid) * 8 + rlo;   // 0..255
        int r = m0 + row; if (r > count - 1) r = count - 1;
        int ga = GATHER ? list[base + r] : r;
        pA[q] = X + (size_t)ga * K + swslot * 8;
    }
    const __hip_bfloat16* pB1[2];
    const __hip_bfloat16* pB3[2];
#pragma unroll
    for (int q = 0; q < 2; ++q) {
        int row = (q * 8 + wid) * 8 + rlo;   // 0..127
        pB1[q] = W1 + ((size_t)e * N + n0 + row) * K + swslot * 8;
        pB3[q] = W3 + ((size_t)e * N + n0 + row) * K + swslot * 8;
    }

#define STAGE_UP(T, BUF) do { const int k0_ = (T) * 64;                         \
    _Pragma("unroll") for (int q = 0; q < 4; ++q)                               \
        gload16(pA[q] + k0_, &As[BUF][(q * 8 + wid) * 512]);                    \
    _Pragma("unroll") for (int q = 0; q < 2; ++q) {                             \
        gload16(pB1[q] + k0_, &B1s[BUF][(q * 8 + wid) * 512]);                  \
        gload16(pB3[q] + k0_, &B3s[BUF][(q * 8 + wid) * 512]); } } while (0)

    const int wm = wid >> 2, wn = wid & 3;
    const int l15 = lane & 15, lhi = lane >> 4;

    f32x4 accg[8][2], accu[8][2];
#pragma unroll
    for (int i = 0; i < 8; ++i)
#pragma unroll
        for (int j = 0; j < 2; ++j) { accg[i][j] = 0.f; accu[i][j] = 0.f; }

    STAGE_UP(0, 0);
    __syncthreads();                         // drains vmcnt: tile 0 landed
    int cur = 0;
#pragma unroll 1
    for (int t = 0; t < NT; ++t) {
        if (t + 1 < NT) STAGE_UP(t + 1, cur ^ 1);
        __builtin_amdgcn_sched_barrier(0);   // pin stage issue before reads
        bfrag b1f[2][2], b3f[2][2];
#pragma unroll
        for (int j = 0; j < 2; ++j)
#pragma unroll
            for (int kk = 0; kk < 2; ++kk) {
                int rb = wn * 32 + j * 16 + l15;
                int c = kk * 4 + lhi;
                int off = rb * 128 + ((c ^ (rb & 7)) << 4);
                b1f[j][kk] = *(const bfrag*)((const char*)B1s[cur] + off);
                b3f[j][kk] = *(const bfrag*)((const char*)B3s[cur] + off);
            }
        __builtin_amdgcn_s_setprio(1);
#pragma unroll
        for (int i = 0; i < 8; ++i) {
            int ra = wm * 128 + i * 16 + l15;
            const char* abase = (const char*)As[cur] + ra * 128;
            bfrag a0 = *(const bfrag*)(abase + ((lhi       ^ (ra & 7)) << 4));
            bfrag a1 = *(const bfrag*)(abase + (((4 + lhi) ^ (ra & 7)) << 4));
#pragma unroll
            for (int j = 0; j < 2; ++j) {
                accg[i][j] = MFMA16(a0, b1f[j][0], accg[i][j]);
                accu[i][j] = MFMA16(a0, b3f[j][0], accu[i][j]);
                accg[i][j] = MFMA16(a1, b1f[j][1], accg[i][j]);
                accu[i][j] = MFMA16(a1, b3f[j][1], accu[i][j]);
            }
        }
        __builtin_amdgcn_s_setprio(0);
        __syncthreads();                     // drain: tile t+1 landed
        cur ^= 1;
    }
#undef STAGE_UP

#pragma unroll
    for (int i = 0; i < 8; ++i)
#pragma unroll
        for (int r = 0; r < 4; ++r) {
            int m = wm * 128 + i * 16 + lhi * 4 + r;
            if (m0 + m < count) {
#pragma unroll
                for (int j = 0; j < 2; ++j) {
                    float gg = accg[i][j][r];
                    float uu = accu[i][j][r];
                    float a = gg / (1.f + __expf(-gg)) * uu;   // silu(g)*u
                    int n = n0 + wn * 32 + j * 16 + l15;
                    act[(size_t)(base + m0 + m) * N + n] = __float2bfloat16(a);
                }
            }
        }
}

// down: out[t] (+)= scale * (A @ W2^T). BM=256, BN=256, BK=64.
template<int KD, bool SCATTER>
__global__ __launch_bounds__(512, 2) void down_v3(
    const __hip_bfloat16* __restrict__ A,     // act [rows][KD]
    const __hip_bfloat16* __restrict__ W2,    // [E][DIM][KD]
    float* __restrict__ out,
    const int* __restrict__ list,
    const int* __restrict__ meta,
    const float* __restrict__ s_e)
{
    constexpr int N = DIM;
    constexpr int NT = KD / 64;
    constexpr int nx = N / 256, ny = T_TOK / 256, nz = SCATTER ? NEXP : 1;
    constexpr int nwg = nx * ny * nz, cpx = nwg / 8;
    const int bid = (int)blockIdx.x + nx * ((int)blockIdx.y + ny * (int)blockIdx.z);
    const int virt = (bid & 7) * cpx + (bid >> 3);
    const int xi = virt % nx;
    const int rest = virt / nx;
    const int yi = rest % ny;
    const int e = rest / ny;

    int count, base;
    if (SCATTER) {
        count = meta[e]; base = meta[16 + e];
        if (yi * 256 >= count) return;
    } else { count = T_TOK; base = 0; }
    const int m0 = yi * 256, n0 = xi * 256;

    __shared__ alignas(16) short As[2][256 * 64];    // 64 KB
    __shared__ alignas(16) short Bs[2][256 * 64];    // 64 KB
    __shared__ int tok_s[256];

    const int tid = threadIdx.x, wid = tid >> 6, lane = tid & 63;
    if (SCATTER && tid < 256) {
        int r = m0 + tid; if (r > count - 1) r = count - 1;
        tok_s[tid] = list[base + r];
    }
    const int rlo = lane >> 3;
    const int swslot = (lane & 7) ^ rlo;

    const __hip_bfloat16* pA[4];
    const __hip_bfloat16* pB[4];
#pragma unroll
    for (int q = 0; q < 4; ++q) {
        int row = (q * 8 + wid) * 8 + rlo;   // 0..255
        int r = m0 + row; if (r > count - 1) r = count - 1;
        pA[q] = A  + (size_t)(base + r) * KD + swslot * 8;
        pB[q] = W2 + ((size_t)e * N + n0 + row) * KD + swslot * 8;
    }

#define STAGE_DN(T, BUF) do { const int k0_ = (T) * 64;                         \
    _Pragma("unroll") for (int q = 0; q < 4; ++q) {                             \
        gload16(pA[q] + k0_, &As[BUF][(q * 8 + wid) * 512]);                    \
        gload16(pB[q] + k0_, &Bs[BUF][(q * 8 + wid) * 512]); } } while (0)

    const int wm = wid >> 2, wn = wid & 3;
    const int l15 = lane & 15, lhi = lane >> 4;

    f32x4 acc[8][4];
#pragma unroll
    for (int i = 0; i < 8; ++i)
#pragma unroll
        for (int j = 0; j < 4; ++j) acc[i][j] = 0.f;

    STAGE_DN(0, 0);
    __syncthreads();
    int cur = 0;
#pragma unroll 1
    for (int t = 0; t < NT; ++t) {
        if (t + 1 < NT) STAGE_DN(t + 1, cur ^ 1);
        __builtin_amdgcn_sched_barrier(0);
        bfrag bf[4][2];
#pragma unroll
        for (int j = 0; j < 4; ++j)
#pragma unroll
            for (int kk = 0; kk < 2; ++kk) {
                int rb = wn * 64 + j * 16 + l15;
                int c = kk * 4 + lhi;
                bf[j][kk] = *(const bfrag*)((const char*)Bs[cur] + rb * 128 + ((c ^ (rb & 7)) << 4));
            }
        __builtin_amdgcn_s_setprio(1);
#pragma unroll
        for (int i = 0; i < 8; ++i) {
            int ra = wm * 128 + i * 16 + l15;
            const char* abase = (const char*)As[cur] + ra * 128;
            bfrag a0 = *(const bfrag*)(abase + ((lhi       ^ (ra & 7)) << 4));
            bfrag a1 = *(const bfrag*)(abase + (((4 + lhi) ^ (ra & 7)) << 4));
#pragma unroll
            for (int j = 0; j < 4; ++j) {
                acc[i][j] = MFMA16(a0, bf[j][0], acc[i][j]);
                acc[i][j] = MFMA16(a1, bf[j][1], acc[i][j]);
            }
        }
        __builtin_amdgcn_s_setprio(0);
        __syncthreads();
        cur ^= 1;
    }
#undef STAGE_DN

    const float scale = SCATTER ? s_e[e] : 1.0f;
#pragma unroll
    for (int i = 0; i < 8; ++i)
#pragma unroll
        for (int r = 0; r < 4; ++r) {
            int m = wm * 128 + i * 16 + lhi * 4 + r;
            if (m0 + m < count) {
#pragma unroll
                for (int j = 0; j < 4; ++j) {
                    int n = n0 + wn * 64 + j * 16 + l15;
                    float v = acc[i][j][r] * scale;
                    if (SCATTER) atomicAdd(&out[(size_t)tok_s[m] * DIM + n], v);
                    else         out[(size_t)(m0 + m) * DIM + n] = v;
                }
            }
        }
}

extern "C" void kernel_launch(void* const* d_in, const int* in_sizes, int n_in,
                              void* d_out, int out_size, void* d_ws, size_t ws_size,
                              hipStream_t stream) {
    const float* x   = (const float*)d_in[0];
    const float* gw  = (const float*)d_in[1];
    const float* w1  = (const float*)d_in[2];
    const float* w3  = (const float*)d_in[3];
    const float* w2  = (const float*)d_in[4];
    const float* sw1 = (const float*)d_in[5];
    const float* sw3 = (const float*)d_in[6];
    const float* sw2 = (const float*)d_in[7];
    float* out = (float*)d_out;

    const size_t SZ_X   = (size_t)T_TOK * DIM * 2;            // 32 MB
    const size_t SZ_W   = (size_t)NEXP * HDIM * DIM * 2;      // 46.1 MB each
    const size_t SZ_SW  = (size_t)SHDIM * DIM * 2;            // 11.5 MB each
    const size_t SZ_ACT = (size_t)2 * T_TOK * HDIM * 2;       // 46.1 MB (== T*SHDIM*2)
    const size_t need = SZ_X + 3 * SZ_W + 3 * SZ_SW + SZ_ACT
                      + (size_t)4 * T_TOK * sizeof(int) + 512;
    if (need > ws_size) return;  // (tier confirmed available in R2)

    char* p = (char*)d_ws;
    __hip_bfloat16* xbf   = (__hip_bfloat16*)p; p += SZ_X;
    __hip_bfloat16* w1bf  = (__hip_bfloat16*)p; p += SZ_W;
    __hip_bfloat16* w3bf  = (__hip_bfloat16*)p; p += SZ_W;
    __hip_bfloat16* w2bf  = (__hip_bfloat16*)p; p += SZ_W;
    __hip_bfloat16* sw1bf = (__hip_bfloat16*)p; p += SZ_SW;
    __hip_bfloat16* sw3bf = (__hip_bfloat16*)p; p += SZ_SW;
    __hip_bfloat16* sw2bf = (__hip_bfloat16*)p; p += SZ_SW;
    __hip_bfloat16* act   = (__hip_bfloat16*)p; p += SZ_ACT;
    int* list = (int*)p; p += (size_t)2 * T_TOK * sizeof(int);
    int* sel  = (int*)p; p += (size_t)2 * T_TOK * sizeof(int);
    int* meta = (int*)p;
    float* s_e = (float*)(meta + 32);

    hipMemsetAsync(meta, 0, 256, stream);
    gate_kernel<<<T_TOK / 32, 256, 0, stream>>>(x, gw, sel, meta, s_e);
    scan_kernel<<<1, 64, 0, stream>>>(meta);
    fill_kernel<<<T_TOK / 256, 256, 0, stream>>>(sel, meta, list);

    cvt_kernel<<<2048, 256, 0, stream>>>(x,   xbf,   T_TOK * DIM / 8);
    cvt_kernel<<<2048, 256, 0, stream>>>(w1,  w1bf,  NEXP * HDIM * DIM / 8);
    cvt_kernel<<<2048, 256, 0, stream>>>(w3,  w3bf,  NEXP * HDIM * DIM / 8);
    cvt_kernel<<<2048, 256, 0, stream>>>(w2,  w2bf,  NEXP * HDIM * DIM / 8);
    cvt_kernel<<<2048, 256, 0, stream>>>(sw1, sw1bf, SHDIM * DIM / 8);
    cvt_kernel<<<2048, 256, 0, stream>>>(sw3, sw3bf, SHDIM * DIM / 8);
    cvt_kernel<<<2048, 256, 0, stream>>>(sw2, sw2bf, SHDIM * DIM / 8);

    // shared expert first (plain stores init out), then sparse experts add
    up_v3<SHDIM, false><<<dim3(SHDIM / 128, T_TOK / 256, 1), 512, 0, stream>>>(
        xbf, sw1bf, sw3bf, act, nullptr, meta);
    down_v3<SHDIM, false><<<dim3(DIM / 256, T_TOK / 256, 1), 512, 0, stream>>>(
        act, sw2bf, out, nullptr, meta, s_e);
    up_v3<HDIM, true><<<dim3(HDIM / 128, T_TOK / 256, NEXP), 512, 0, stream>>>(
        xbf, w1bf, w3bf, act, list, meta);
    down_v3<HDIM, true><<<dim3(DIM / 256, T_TOK / 256, NEXP), 512, 0, stream>>>(
        act, w2bf, out, list, meta, s_e);
}